// Round 18
// baseline (262.025 us; speedup 1.0000x reference)
//
#include <hip/hip_runtime.h>
#include <float.h>
#include <limits.h>

// N=131072, K=2048, D=64.
// Verified reference scheme R (rounds 5/7/9-17, absmax 0.0):
//   xsq: numpy NPY_SIMD-128 pairwise (8 vec-accs x 4 lanes + SSE3 hadd tree)
//   esq: scalar pairwise-8; dot: any fp32 order (proven); 
//   dist=fl(fl(xsq+esq)-2dot); argmin first-index.
// Round 18: REGISTER-RESIDENT B. Each of 8 waves owns 256 codes; their
// bf16(-2e) fragments live in 128 VGPRs, loaded once per block (256KB from
// L2, issued at kernel top). A (128 rows) converted once to a swizzled bf16
// LDS image. Main loops: 8 row-tiles x 16 col-tiles x 2 MFMA = 512 MFMA/wave
// per pass from 16 ds_read_b128 — ZERO barriers / staging in steady state
// (vs 64 barrier-phases in R13/R17, each a ~2K-cy latency convoy).
// Algorithm unchanged: folded -2e screen, pass1 min -> thr, pass2 register
// replay collect, exact R rescore (x from global), lossless fallback.
#define D_DIM 64
#define K_CB  2048
#define BM    128
#define NTHREADS 512
#define NWAVES 8
#define CPW   256               // codes per wave
#define CT    16                // col-tiles per wave
#define RT    8                 // row-tiles per block
#define MARGIN 2e-3f
#define CAND_CAP 24

typedef __attribute__((ext_vector_type(4))) float f32x4;
typedef __attribute__((ext_vector_type(8))) short s16x8;

__device__ __forceinline__ short f2bf(float f) {   // RN-even fp32->bf16 bits
  unsigned u = __builtin_bit_cast(unsigned, f);
  u += 0x7fffu + ((u >> 16) & 1u);
  return (short)(unsigned short)(u >> 16);
}

// prep: esq[k] (scalar-8 numpy order, verified) + PLAIN row-major bf16(-2*e)
// (no swizzle: B is loaded straight to registers now).
__global__ void __launch_bounds__(256) prep_kernel(const float* __restrict__ cb,
                                                   float* __restrict__ esq,
                                                   unsigned short* __restrict__ cbh) {
#pragma clang fp contract(off)
  int k = blockIdx.x * 256 + threadIdx.x;
  if (k >= K_CB) return;
  const float* row = cb + (size_t)k * D_DIM;
  float r[8];
#pragma unroll
  for (int j = 0; j < 8; ++j) { float v = row[j]; r[j] = v * v; }
#pragma unroll
  for (int i = 1; i < 8; ++i)
#pragma unroll
    for (int j = 0; j < 8; ++j) { float v = row[8 * i + j]; r[j] += v * v; }
  esq[k] = ((r[0] + r[1]) + (r[2] + r[3])) + ((r[4] + r[5]) + (r[6] + r[7]));
  unsigned short* o = cbh + (size_t)k * D_DIM;
#pragma unroll
  for (int d = 0; d < D_DIM; ++d)
    o[d] = (unsigned short)f2bf(-2.0f * row[d]);
}

__global__ void __launch_bounds__(NTHREADS)
vq_mfma_kernel(const float* __restrict__ x,
               const float* __restrict__ cb,
               const float* __restrict__ esq,
               const unsigned short* __restrict__ cbh,
               float* __restrict__ out) {
#pragma clang fp contract(off)
  __shared__ float4 xs4[BM * 16];           // 32 KB fp32 x tile (swizzled)
  __shared__ unsigned short abf[BM * 64];   // 16 KB bf16 A image (swizzled)
  __shared__ int   cand_s[BM * CAND_CAP];   // 12 KB
  __shared__ float rowmin_s[NWAVES][BM];    // 4 KB
  __shared__ float rowthr_s[BM];
  __shared__ float xsq_s[BM];
  __shared__ int   cnt_s[BM];
  __shared__ int   bestk_s[BM];
  __shared__ int   ovf_rows[BM];
  __shared__ int   ovf_cnt;
  __shared__ float fb_v[NWAVES];
  __shared__ int   fb_k[NWAVES];

  const int tid  = threadIdx.x;
  const int lane = tid & 63;
  const int wave = tid >> 6;
  const int row0 = blockIdx.x * BM;
  const int ccol = lane & 15;
  const int kg   = (lane >> 4) * 8;

  // ---- B fragments -> registers (issued first; latency hides under prologue)
  // code c = wave*CPW + ct*16 + ccol; b0 = elems [kg,kg+8), b1 = [32+kg,..)
  s16x8 b0f[CT], b1f[CT];
  {
    const unsigned short* wb = cbh + (size_t)(wave * CPW + ccol) * D_DIM;
#pragma unroll
    for (int ct = 0; ct < CT; ++ct) {
      b0f[ct] = *(const s16x8*)(wb + ct * 16 * D_DIM + kg);
      b1f[ct] = *(const s16x8*)(wb + ct * 16 * D_DIM + 32 + kg);
    }
  }

  // ---- stage x tile (coalesced float4), swizzle float4-col ^= (row>>2)&7 ----
  const float4* xg = (const float4*)(x + (size_t)row0 * D_DIM);
#pragma unroll
  for (int i = 0; i < 4; ++i) {
    int f = tid + i * NTHREADS;             // 2048 float4
    int row = f >> 4, c4 = f & 15;
    xs4[row * 16 + (c4 ^ ((row >> 2) & 7))] = xg[f];
  }
  if (tid == 0) ovf_cnt = 0;
  if (tid < BM) cnt_s[tid] = 0;
  __syncthreads();

  // ---- xsq per row: numpy NPY_SIMD-128 pairwise emulation (verified R5) ----
  if (tid < BM) {
    const int swz = 4 * ((tid >> 2) & 7);
    const float* xr = (const float*)xs4 + tid * 64;
    float s[4];
#pragma unroll
    for (int l = 0; l < 4; ++l) {
      float rj[8];
#pragma unroll
      for (int j = 0; j < 8; ++j) {
        float a = xr[(4 * j + l) ^ swz];
        float b = xr[(32 + 4 * j + l) ^ swz];
        float ta = a * a;
        float tb = b * b;
        rj[j] = ta + tb;
      }
      s[l] = ((rj[0] + rj[1]) + (rj[2] + rj[3])) +
             ((rj[4] + rj[5]) + (rj[6] + rj[7]));
    }
    xsq_s[tid] = (s[0] + s[1]) + (s[2] + s[3]);
  }

  // ---- convert x tile to bf16 A image, swizzle elem d ^= (row&7)<<3 ----
  // (write+read both swizzled => 2-way bank aliasing on reads = free)
#pragma unroll
  for (int i = 0; i < 16; ++i) {
    int e = tid + i * NTHREADS;             // 8192 elements
    int row = e >> 6, d = e & 63;
    float v = ((const float*)xs4)[row * 64 + (((d >> 2) ^ ((row >> 2) & 7)) * 4 + (d & 3))];
    abf[row * 64 + (d ^ ((row & 7) << 3))] = (unsigned short)f2bf(v);
  }
  __syncthreads();

  // ================= pass 1: per-row screen min (NO barriers) =================
  const int arow = lane & 15;
  float minv[RT][4];
#pragma unroll
  for (int rt = 0; rt < RT; ++rt)
#pragma unroll
    for (int r = 0; r < 4; ++r) minv[rt][r] = FLT_MAX;

#pragma unroll
  for (int rt = 0; rt < RT; ++rt) {
    int row = rt * 16 + arow;
    int sw = (row & 7) << 3;
    s16x8 a0 = *(const s16x8*)(abf + row * 64 + (kg ^ sw));
    s16x8 a1 = *(const s16x8*)(abf + row * 64 + ((32 + kg) ^ sw));
#pragma unroll
    for (int ct = 0; ct < CT; ++ct) {
      f32x4 acc = {0.f, 0.f, 0.f, 0.f};
      acc = __builtin_amdgcn_mfma_f32_16x16x32_bf16(a0, b0f[ct], acc, 0, 0, 0);
      acc = __builtin_amdgcn_mfma_f32_16x16x32_bf16(a1, b1f[ct], acc, 0, 0, 0);
#pragma unroll
      for (int r = 0; r < 4; ++r) minv[rt][r] = fminf(minv[rt][r], acc[r]);
    }
  }

  // cross-lane min over the 16 cols; write this wave's per-row partials
#pragma unroll
  for (int rt = 0; rt < RT; ++rt)
#pragma unroll
    for (int r = 0; r < 4; ++r) {
      float v = minv[rt][r];
#pragma unroll
      for (int m = 1; m <= 8; m <<= 1) v = fminf(v, __shfl_xor(v, m));
      minv[rt][r] = v;
    }
  if ((lane & 15) == 0) {
#pragma unroll
    for (int rt = 0; rt < RT; ++rt)
#pragma unroll
      for (int r = 0; r < 4; ++r)
        rowmin_s[wave][rt * 16 + (lane >> 4) * 4 + r] = minv[rt][r];
  }
  __syncthreads();
  if (tid < BM) {
    float m = rowmin_s[0][tid];
#pragma unroll
    for (int w = 1; w < NWAVES; ++w) m = fminf(m, rowmin_s[w][tid]);
    rowthr_s[tid] = m + MARGIN;
  }
  __syncthreads();

  // thr into the (dead) minv registers
#pragma unroll
  for (int rt = 0; rt < RT; ++rt)
#pragma unroll
    for (int r = 0; r < 4; ++r)
      minv[rt][r] = rowthr_s[rt * 16 + (lane >> 4) * 4 + r];

  // ====== pass 2: register replay (bit-identical), collect candidates ======
#pragma unroll
  for (int rt = 0; rt < RT; ++rt) {
    int row = rt * 16 + arow;
    int sw = (row & 7) << 3;
    s16x8 a0 = *(const s16x8*)(abf + row * 64 + (kg ^ sw));
    s16x8 a1 = *(const s16x8*)(abf + row * 64 + ((32 + kg) ^ sw));
#pragma unroll
    for (int ct = 0; ct < CT; ++ct) {
      f32x4 acc = {0.f, 0.f, 0.f, 0.f};
      acc = __builtin_amdgcn_mfma_f32_16x16x32_bf16(a0, b0f[ct], acc, 0, 0, 0);
      acc = __builtin_amdgcn_mfma_f32_16x16x32_bf16(a1, b1f[ct], acc, 0, 0, 0);
#pragma unroll
      for (int r = 0; r < 4; ++r) {
        if (acc[r] <= minv[rt][r]) {
          int row2 = rt * 16 + (lane >> 4) * 4 + r;
          int pos = atomicAdd(&cnt_s[row2], 1);
          if (pos < CAND_CAP)
            cand_s[row2 * CAND_CAP + pos] = wave * CPW + ct * 16 + ccol;
        }
      }
    }
  }
  __syncthreads();

  // ====== exact rescore (R-scheme), lex-(dist,k); 4 threads per row.
  //        x from GLOBAL (linear d-order: verified-passing order). ======
  {
    const int row = tid >> 2, slot = tid & 3;
    const int cnt = cnt_s[row];
    if (cnt <= CAND_CAP) {
      const float* xr = x + (size_t)(row0 + row) * D_DIM;
      const float xq = xsq_s[row];
      float bv = FLT_MAX; int bk = INT_MAX;
      for (int i = slot; i < cnt; i += 4) {
        int k = cand_s[row * CAND_CAP + i];
        const float* er = cb + (size_t)k * D_DIM;
        float a = 0.f;
#pragma unroll 8
        for (int d = 0; d < D_DIM; ++d) a = fmaf(xr[d], er[d], a);
        float dist = (xq + esq[k]) - 2.0f * a;
        if (dist < bv || (dist == bv && k < bk)) { bv = dist; bk = k; }
      }
#pragma unroll
      for (int m = 1; m <= 2; m <<= 1) {
        float ov = __shfl_xor(bv, m); int ok = __shfl_xor(bk, m);
        if (ov < bv || (ov == bv && ok < bk)) { bv = ov; bk = ok; }
      }
      if (slot == 0) bestk_s[row] = bk;
    }
  }
  if (tid < BM && cnt_s[tid] > CAND_CAP) {
    int p = atomicAdd(&ovf_cnt, 1);
    ovf_rows[p] = tid;
  }
  __syncthreads();

  // ====== lossless overflow fallback: block-cooperative full scan ======
  {
    const int novf = ovf_cnt;
    for (int i = 0; i < novf; ++i) {
      const int row = ovf_rows[i];
      const float* xr = x + (size_t)(row0 + row) * D_DIM;
      const float xq = xsq_s[row];
      float bv = FLT_MAX; int bk = INT_MAX;
      for (int k = tid; k < K_CB; k += NTHREADS) {
        const float* er = cb + (size_t)k * D_DIM;
        float a = 0.f;
#pragma unroll 8
        for (int d = 0; d < D_DIM; ++d) a = fmaf(xr[d], er[d], a);
        float dist = (xq + esq[k]) - 2.0f * a;
        if (dist < bv || (dist == bv && k < bk)) { bv = dist; bk = k; }
      }
#pragma unroll
      for (int m = 1; m <= 32; m <<= 1) {
        float ov = __shfl_xor(bv, m); int ok = __shfl_xor(bk, m);
        if (ov < bv || (ov == bv && ok < bk)) { bv = ov; bk = ok; }
      }
      if (lane == 0) { fb_v[wave] = bv; fb_k[wave] = bk; }
      __syncthreads();
      if (tid == 0) {
        float BV = fb_v[0]; int BK = fb_k[0];
#pragma unroll
        for (int w = 1; w < NWAVES; ++w)
          if (fb_v[w] < BV || (fb_v[w] == BV && fb_k[w] < BK)) { BV = fb_v[w]; BK = fb_k[w]; }
        bestk_s[row] = BK;
      }
      __syncthreads();
    }
  }
  __syncthreads();

  // ---- gather: out[row] = codebook[bestk[row]], coalesced float4 ----
  const float4* cb4 = (const float4*)cb;
  float4* out4 = (float4*)out + (size_t)row0 * 16;
#pragma unroll
  for (int i = 0; i < 4; ++i) {
    int f = tid + i * NTHREADS;
    int row = f >> 4, c4 = f & 15;
    out4[f] = cb4[(size_t)bestk_s[row] * 16 + c4];
  }
}

extern "C" void kernel_launch(void* const* d_in, const int* in_sizes, int n_in,
                              void* d_out, int out_size, void* d_ws, size_t ws_size,
                              hipStream_t stream) {
  const float* x  = (const float*)d_in[0];   // [N, 64] fp32
  const float* cb = (const float*)d_in[1];   // [2048, 64] fp32
  float* out = (float*)d_out;                // [N, 64] fp32
  float* esq = (float*)d_ws;                 // [2048] fp32
  unsigned short* cbh = (unsigned short*)d_ws + 4096;  // plain bf16(-2e), 256 KB

  const int N = in_sizes[0] / D_DIM;         // 131072

  prep_kernel<<<(K_CB + 255) / 256, 256, 0, stream>>>(cb, esq, cbh);
  vq_mfma_kernel<<<N / BM, NTHREADS, 0, stream>>>(x, cb, esq, cbh, out);
}

// Round 19
// 198.875 us; speedup vs baseline: 1.3175x; 1.3175x over previous
//
#include <hip/hip_runtime.h>
#include <float.h>
#include <limits.h>

// N=131072, K=2048, D=64.
// Verified reference scheme R (rounds 5/7/9-17, absmax 0.0):
//   xsq: numpy NPY_SIMD-128 pairwise (8 vec-accs x 4 lanes + SSE3 hadd tree)
//   esq: scalar pairwise-8; dot: any fp32 order (proven);
//   dist=fl(fl(xsq+esq)-2dot); argmin first-index.
// Round 19 = R17's algorithm at maximum-occupancy geometry. Evidence: R13
// (64 phases, thin) = 202us, R17 (64 phases, 4x work/phase) = 199us -> wall
// == phases x per-phase latency; per-phase latency tracks resident waves,
// capped at 2 blocks/CU by LDS in every prior design. This round: BM=128 /
// 512 thr / 8 waves x 1 row-tile, overlay x-tile(32K) >= bbuf(16K)+cand(12K)
// -> static LDS ~35 KB -> 4 blocks/CU = 32 waves/CU; 1024 blocks co-resident
// in one batch. R18's register-B reverted (VGPR 112 < 128 -> remat, 262us).
// Algorithm unchanged: folded -2e bf16 MFMA screen, 2-pass margin collect,
// exact R rescore (x from global), lossless block-cooperative fallback.
#define D_DIM 64
#define K_CB  2048
#define BM    128
#define NTHREADS 512
#define NWAVES 8
#define KT    64                // codes per staged tile (8 KB)
#define NT    (K_CB / KT)       // 32 tiles
#define MARGIN 2e-3f
#define CAND_CAP 24

typedef __attribute__((ext_vector_type(4))) float f32x4;
typedef __attribute__((ext_vector_type(8))) short s16x8;

__device__ __forceinline__ short f2bf(float f) {   // RN-even fp32->bf16 bits
  unsigned u = __builtin_bit_cast(unsigned, f);
  u += 0x7fffu + ((u >> 16) & 1u);
  return (short)(unsigned short)(u >> 16);
}

__device__ __forceinline__ void gload_lds16(const void* g, void* l) {
  __builtin_amdgcn_global_load_lds(
      (const __attribute__((address_space(1))) unsigned int*)g,
      (__attribute__((address_space(3))) unsigned int*)l, 16, 0, 0);
}

// prep: esq[k] (scalar-8 numpy order, verified) + bf16(-2*e) PRE-SWIZZLED:
//   cbh[k*64 + (d ^ ((k&7)<<3))] = bf16(-2*cb[k][d])
__global__ void __launch_bounds__(256) prep_kernel(const float* __restrict__ cb,
                                                   float* __restrict__ esq,
                                                   unsigned short* __restrict__ cbh) {
#pragma clang fp contract(off)
  int k = blockIdx.x * 256 + threadIdx.x;
  if (k >= K_CB) return;
  const float* row = cb + (size_t)k * D_DIM;
  float r[8];
#pragma unroll
  for (int j = 0; j < 8; ++j) { float v = row[j]; r[j] = v * v; }
#pragma unroll
  for (int i = 1; i < 8; ++i)
#pragma unroll
    for (int j = 0; j < 8; ++j) { float v = row[8 * i + j]; r[j] += v * v; }
  esq[k] = ((r[0] + r[1]) + (r[2] + r[3])) + ((r[4] + r[5]) + (r[6] + r[7]));
  unsigned short* o = cbh + (size_t)k * D_DIM;
  const int sw = (k & 7) << 3;
#pragma unroll
  for (int d = 0; d < D_DIM; ++d)
    o[d ^ sw] = (unsigned short)f2bf(-2.0f * row[d]);
}

__global__ void __launch_bounds__(NTHREADS)
vq_mfma_kernel(const float* __restrict__ x,
               const float* __restrict__ cb,
               const float* __restrict__ esq,
               const unsigned short* __restrict__ cbh,
               float* __restrict__ out) {
#pragma clang fp contract(off)
  // Overlay: prologue = fp32 x tile (32 KB); steady = bbuf[2] (16 KB) +
  // cand_s (12 KB). x tile is dead after xsq + A-fragment extraction.
  __shared__ __align__(16) char smem[32768];
  __shared__ float xsq_s[BM];
  __shared__ float rowthr_s[BM];
  __shared__ int   cnt_s[BM];
  __shared__ int   bestk_s[BM];
  __shared__ int   ovf_rows[BM];
  __shared__ int   ovf_cnt;
  __shared__ float fb_v[NWAVES];
  __shared__ int   fb_k[NWAVES];

  const int tid  = threadIdx.x;
  const int lane = tid & 63;
  const int wave = tid >> 6;
  const int row0 = blockIdx.x * BM;

  float4* xs4 = (float4*)smem;                     // prologue view

  // ---- stage x tile (coalesced float4), swizzle float4-col ^= (row>>2)&7 ----
  const float4* xg = (const float4*)(x + (size_t)row0 * D_DIM);
#pragma unroll
  for (int i = 0; i < 4; ++i) {
    int f = tid + i * NTHREADS;                    // 2048 float4
    int row = f >> 4, c4 = f & 15;
    xs4[row * 16 + (c4 ^ ((row >> 2) & 7))] = xg[f];
  }
  if (tid == 0) ovf_cnt = 0;
  if (tid < BM) cnt_s[tid] = 0;
  __syncthreads();

  // ---- xsq per row: numpy NPY_SIMD-128 pairwise emulation (verified R5) ----
  if (tid < BM) {
    const int swz = 4 * ((tid >> 2) & 7);
    const float* xr = (const float*)xs4 + tid * 64;
    float s[4];
#pragma unroll
    for (int l = 0; l < 4; ++l) {
      float rj[8];
#pragma unroll
      for (int j = 0; j < 8; ++j) {
        float a = xr[(4 * j + l) ^ swz];
        float b = xr[(32 + 4 * j + l) ^ swz];
        float ta = a * a;
        float tb = b * b;
        rj[j] = ta + tb;
      }
      s[l] = ((rj[0] + rj[1]) + (rj[2] + rj[3])) +
             ((rj[4] + rj[5]) + (rj[6] + rj[7]));
    }
    xsq_s[tid] = (s[0] + s[1]) + (s[2] + s[3]);
  }

  // ---- A fragments: wave owns rows wave*16..wave*16+15 (m89-verified maps:
  //   A: lane row=lane&15, k=(lane>>4)*8+j; B: col=lane&15, same k;
  //   C: col=lane&15, row=(lane>>4)*4+r)
  s16x8 a0, a1;
  {
    const int arow = lane & 15;
    const int kgA = (lane >> 4) * 8;
    const int row = wave * 16 + arow;
    const int sw = (row >> 2) & 7;
    {
      int q0 = kgA >> 2;
      float4 f0 = xs4[row * 16 + (q0 ^ sw)];
      float4 f1 = xs4[row * 16 + ((q0 + 1) ^ sw)];
      a0[0] = f2bf(f0.x); a0[1] = f2bf(f0.y); a0[2] = f2bf(f0.z); a0[3] = f2bf(f0.w);
      a0[4] = f2bf(f1.x); a0[5] = f2bf(f1.y); a0[6] = f2bf(f1.z); a0[7] = f2bf(f1.w);
    }
    {
      int q0 = (32 + kgA) >> 2;
      float4 f0 = xs4[row * 16 + (q0 ^ sw)];
      float4 f1 = xs4[row * 16 + ((q0 + 1) ^ sw)];
      a1[0] = f2bf(f0.x); a1[1] = f2bf(f0.y); a1[2] = f2bf(f0.z); a1[3] = f2bf(f0.w);
      a1[4] = f2bf(f1.x); a1[5] = f2bf(f1.y); a1[6] = f2bf(f1.z); a1[7] = f2bf(f1.w);
    }
  }
  __syncthreads();   // x tile dead; smem becomes bbuf + cand_s

  int* cand_s = (int*)(smem + 16384);              // [BM * CAND_CAP] = 12 KB

  const int ccol = lane & 15;
  const int kg   = (lane >> 4) * 8;
  const int swb  = (ccol & 7) << 3;                // lane-constant
  const int rowbase = wave * 16 + (lane >> 4) * 4;

  // stage tile t into buffer b: 8 KB = 512 threads x 16B
  auto STAGE = [&](int t, int b) {
    const char* s0 = (const char*)cbh + (size_t)t * 8192 + wave * 1024 + lane * 16;
    char* d0 = smem + b * 8192 + wave * 1024;
    gload_lds16(s0, d0);
  };

  // ================= pass 1: per-row screen min =================
  float minv[4];
  minv[0] = minv[1] = minv[2] = minv[3] = FLT_MAX;

  STAGE(0, 0);
  __syncthreads();
  for (int t = 0; t < NT; ++t) {
    if (t + 1 < NT) STAGE(t + 1, (t + 1) & 1);
    const unsigned short* B = (const unsigned short*)(smem + (t & 1) * 8192);
#pragma unroll
    for (int st = 0; st < 4; ++st) {
      const unsigned short* bp = B + (st * 16 + ccol) * 64;
      s16x8 b0 = *(const s16x8*)(bp + (kg ^ swb));
      s16x8 b1 = *(const s16x8*)(bp + ((32 + kg) ^ swb));
      f32x4 acc = {0.f, 0.f, 0.f, 0.f};
      acc = __builtin_amdgcn_mfma_f32_16x16x32_bf16(a0, b0, acc, 0, 0, 0);
      acc = __builtin_amdgcn_mfma_f32_16x16x32_bf16(a1, b1, acc, 0, 0, 0);
#pragma unroll
      for (int r = 0; r < 4; ++r) minv[r] = fminf(minv[r], acc[r]);
    }
    __syncthreads();
  }

  // per-row min across the 16 covering lanes (rows are wave-private)
#pragma unroll
  for (int r = 0; r < 4; ++r) {
    float v = minv[r];
#pragma unroll
    for (int m = 1; m <= 8; m <<= 1) v = fminf(v, __shfl_xor(v, m));
    minv[r] = v;
  }
  if ((lane & 15) == 0) {
#pragma unroll
    for (int r = 0; r < 4; ++r)
      rowthr_s[rowbase + r] = minv[r] + MARGIN;
  }
  __syncthreads();

  float thr[4];
#pragma unroll
  for (int r = 0; r < 4; ++r)
    thr[r] = rowthr_s[rowbase + r];

  // ====== pass 2: recompute (bit-identical), collect candidates ======
  STAGE(0, 0);
  __syncthreads();
  for (int t = 0; t < NT; ++t) {
    if (t + 1 < NT) STAGE(t + 1, (t + 1) & 1);
    const unsigned short* B = (const unsigned short*)(smem + (t & 1) * 8192);
#pragma unroll
    for (int st = 0; st < 4; ++st) {
      const unsigned short* bp = B + (st * 16 + ccol) * 64;
      s16x8 b0 = *(const s16x8*)(bp + (kg ^ swb));
      s16x8 b1 = *(const s16x8*)(bp + ((32 + kg) ^ swb));
      f32x4 acc = {0.f, 0.f, 0.f, 0.f};
      acc = __builtin_amdgcn_mfma_f32_16x16x32_bf16(a0, b0, acc, 0, 0, 0);
      acc = __builtin_amdgcn_mfma_f32_16x16x32_bf16(a1, b1, acc, 0, 0, 0);
#pragma unroll
      for (int r = 0; r < 4; ++r) {
        if (acc[r] <= thr[r]) {
          int row = rowbase + r;
          int pos = atomicAdd(&cnt_s[row], 1);
          if (pos < CAND_CAP) cand_s[row * CAND_CAP + pos] = t * 64 + st * 16 + ccol;
        }
      }
    }
    __syncthreads();
  }

  // ====== exact rescore (R-scheme), lex-(dist,k); 4 threads per row.
  //        x read from GLOBAL (linear d-order: verified-passing order). ======
  {
    const int row = tid >> 2, slot = tid & 3;
    const int cnt = cnt_s[row];
    if (cnt <= CAND_CAP) {
      const float* xr = x + (size_t)(row0 + row) * D_DIM;
      const float xq = xsq_s[row];
      float bv = FLT_MAX; int bk = INT_MAX;
      for (int i = slot; i < cnt; i += 4) {
        int k = cand_s[row * CAND_CAP + i];
        const float* er = cb + (size_t)k * D_DIM;
        float a = 0.f;
#pragma unroll 8
        for (int d = 0; d < D_DIM; ++d) a = fmaf(xr[d], er[d], a);
        float dist = (xq + esq[k]) - 2.0f * a;
        if (dist < bv || (dist == bv && k < bk)) { bv = dist; bk = k; }
      }
#pragma unroll
      for (int m = 1; m <= 2; m <<= 1) {
        float ov = __shfl_xor(bv, m); int ok = __shfl_xor(bk, m);
        if (ov < bv || (ov == bv && ok < bk)) { bv = ov; bk = ok; }
      }
      if (slot == 0) bestk_s[row] = bk;
    }
  }
  if (tid < BM && cnt_s[tid] > CAND_CAP) {
    int p = atomicAdd(&ovf_cnt, 1);
    ovf_rows[p] = tid;
  }
  __syncthreads();

  // ====== lossless overflow fallback: block-cooperative full scan ======
  {
    const int novf = ovf_cnt;
    for (int i = 0; i < novf; ++i) {
      const int row = ovf_rows[i];
      const float* xr = x + (size_t)(row0 + row) * D_DIM;
      const float xq = xsq_s[row];
      float bv = FLT_MAX; int bk = INT_MAX;
      for (int k = tid; k < K_CB; k += NTHREADS) {
        const float* er = cb + (size_t)k * D_DIM;
        float a = 0.f;
#pragma unroll 8
        for (int d = 0; d < D_DIM; ++d) a = fmaf(xr[d], er[d], a);
        float dist = (xq + esq[k]) - 2.0f * a;
        if (dist < bv || (dist == bv && k < bk)) { bv = dist; bk = k; }
      }
#pragma unroll
      for (int m = 1; m <= 32; m <<= 1) {
        float ov = __shfl_xor(bv, m); int ok = __shfl_xor(bk, m);
        if (ov < bv || (ov == bv && ok < bk)) { bv = ov; bk = ok; }
      }
      if (lane == 0) { fb_v[wave] = bv; fb_k[wave] = bk; }
      __syncthreads();
      if (tid == 0) {
        float BV = fb_v[0]; int BK = fb_k[0];
#pragma unroll
        for (int w = 1; w < NWAVES; ++w)
          if (fb_v[w] < BV || (fb_v[w] == BV && fb_k[w] < BK)) { BV = fb_v[w]; BK = fb_k[w]; }
        bestk_s[row] = BK;
      }
      __syncthreads();
    }
  }
  __syncthreads();

  // ---- gather: out[row] = codebook[bestk[row]], coalesced float4 ----
  const float4* cb4 = (const float4*)cb;
  float4* out4 = (float4*)out + (size_t)row0 * 16;
#pragma unroll
  for (int i = 0; i < 4; ++i) {
    int f = tid + i * NTHREADS;
    int row = f >> 4, c4 = f & 15;
    out4[f] = cb4[(size_t)bestk_s[row] * 16 + c4];
  }
}

extern "C" void kernel_launch(void* const* d_in, const int* in_sizes, int n_in,
                              void* d_out, int out_size, void* d_ws, size_t ws_size,
                              hipStream_t stream) {
  const float* x  = (const float*)d_in[0];   // [N, 64] fp32
  const float* cb = (const float*)d_in[1];   // [2048, 64] fp32
  float* out = (float*)d_out;                // [N, 64] fp32
  float* esq = (float*)d_ws;                 // [2048] fp32
  unsigned short* cbh = (unsigned short*)d_ws + 4096;  // swizzled bf16(-2e), 256 KB

  const int N = in_sizes[0] / D_DIM;         // 131072

  prep_kernel<<<(K_CB + 255) / 256, 256, 0, stream>>>(cb, esq, cbh);
  vq_mfma_kernel<<<N / BM, NTHREADS, 0, stream>>>(x, cb, esq, cbh, out);
}

// Round 20
// 187.085 us; speedup vs baseline: 1.4006x; 1.0630x over previous
//
#include <hip/hip_runtime.h>
#include <float.h>
#include <limits.h>

// N=131072, K=2048, D=64.
// Verified reference scheme R (rounds 5/7/9-19, absmax 0.0):
//   xsq: numpy NPY_SIMD-128 pairwise (8 vec-accs x 4 lanes + SSE3 hadd tree)
//   esq: scalar pairwise-8; dot: any fp32 order (proven);
//   dist=fl(fl(xsq+esq)-2dot); argmin first-index.
// Round 20: PHASE-COUNT test. Plateau series: R13 (64 phases, thin) 202us;
// R17 (64 phases, 4x work/phase) 199; R19 (64 phases, 2x blocks/CU) 199.
// Only phase count tracks the wall -> halve it: KT 64->128, 16 phases/pass
// (32 total), 16KB staged per phase, 8 subtiles (16 MFMA/wave) per phase.
// LDS: overlay 32KB (x-tile >= bbuf 2x16KB) + cand 12KB => ~47.6KB, 3
// blocks/CU. Algorithm unchanged: folded -2e bf16 MFMA screen, 2-pass
// margin collect, exact R rescore (x from global), lossless fallback.
#define D_DIM 64
#define K_CB  2048
#define BM    128
#define NTHREADS 512
#define NWAVES 8
#define KT    128               // codes per staged tile (16 KB)
#define NT    (K_CB / KT)       // 16 tiles
#define MARGIN 2e-3f
#define CAND_CAP 24

typedef __attribute__((ext_vector_type(4))) float f32x4;
typedef __attribute__((ext_vector_type(8))) short s16x8;

__device__ __forceinline__ short f2bf(float f) {   // RN-even fp32->bf16 bits
  unsigned u = __builtin_bit_cast(unsigned, f);
  u += 0x7fffu + ((u >> 16) & 1u);
  return (short)(unsigned short)(u >> 16);
}

__device__ __forceinline__ void gload_lds16(const void* g, void* l) {
  __builtin_amdgcn_global_load_lds(
      (const __attribute__((address_space(1))) unsigned int*)g,
      (__attribute__((address_space(3))) unsigned int*)l, 16, 0, 0);
}

// prep: esq[k] (scalar-8 numpy order, verified) + bf16(-2*e) PRE-SWIZZLED:
//   cbh[k*64 + (d ^ ((k&7)<<3))] = bf16(-2*cb[k][d])
__global__ void __launch_bounds__(256) prep_kernel(const float* __restrict__ cb,
                                                   float* __restrict__ esq,
                                                   unsigned short* __restrict__ cbh) {
#pragma clang fp contract(off)
  int k = blockIdx.x * 256 + threadIdx.x;
  if (k >= K_CB) return;
  const float* row = cb + (size_t)k * D_DIM;
  float r[8];
#pragma unroll
  for (int j = 0; j < 8; ++j) { float v = row[j]; r[j] = v * v; }
#pragma unroll
  for (int i = 1; i < 8; ++i)
#pragma unroll
    for (int j = 0; j < 8; ++j) { float v = row[8 * i + j]; r[j] += v * v; }
  esq[k] = ((r[0] + r[1]) + (r[2] + r[3])) + ((r[4] + r[5]) + (r[6] + r[7]));
  unsigned short* o = cbh + (size_t)k * D_DIM;
  const int sw = (k & 7) << 3;
#pragma unroll
  for (int d = 0; d < D_DIM; ++d)
    o[d ^ sw] = (unsigned short)f2bf(-2.0f * row[d]);
}

__global__ void __launch_bounds__(NTHREADS)
vq_mfma_kernel(const float* __restrict__ x,
               const float* __restrict__ cb,
               const float* __restrict__ esq,
               const unsigned short* __restrict__ cbh,
               float* __restrict__ out) {
#pragma clang fp contract(off)
  // Overlay: prologue = fp32 x tile (32 KB); steady = bbuf[2] (2x16 KB).
  __shared__ __align__(16) char smem[32768];
  __shared__ int   cand_s[BM * CAND_CAP];          // 12 KB (not overlaid)
  __shared__ float xsq_s[BM];
  __shared__ float rowthr_s[BM];
  __shared__ int   cnt_s[BM];
  __shared__ int   bestk_s[BM];
  __shared__ int   ovf_rows[BM];
  __shared__ int   ovf_cnt;
  __shared__ float fb_v[NWAVES];
  __shared__ int   fb_k[NWAVES];

  const int tid  = threadIdx.x;
  const int lane = tid & 63;
  const int wave = tid >> 6;
  const int row0 = blockIdx.x * BM;

  float4* xs4 = (float4*)smem;                     // prologue view

  // ---- stage x tile (coalesced float4), swizzle float4-col ^= (row>>2)&7 ----
  const float4* xg = (const float4*)(x + (size_t)row0 * D_DIM);
#pragma unroll
  for (int i = 0; i < 4; ++i) {
    int f = tid + i * NTHREADS;                    // 2048 float4
    int row = f >> 4, c4 = f & 15;
    xs4[row * 16 + (c4 ^ ((row >> 2) & 7))] = xg[f];
  }
  if (tid == 0) ovf_cnt = 0;
  if (tid < BM) cnt_s[tid] = 0;
  __syncthreads();

  // ---- xsq per row: numpy NPY_SIMD-128 pairwise emulation (verified R5) ----
  if (tid < BM) {
    const int swz = 4 * ((tid >> 2) & 7);
    const float* xr = (const float*)xs4 + tid * 64;
    float s[4];
#pragma unroll
    for (int l = 0; l < 4; ++l) {
      float rj[8];
#pragma unroll
      for (int j = 0; j < 8; ++j) {
        float a = xr[(4 * j + l) ^ swz];
        float b = xr[(32 + 4 * j + l) ^ swz];
        float ta = a * a;
        float tb = b * b;
        rj[j] = ta + tb;
      }
      s[l] = ((rj[0] + rj[1]) + (rj[2] + rj[3])) +
             ((rj[4] + rj[5]) + (rj[6] + rj[7]));
    }
    xsq_s[tid] = (s[0] + s[1]) + (s[2] + s[3]);
  }

  // ---- A fragments: wave owns rows wave*16..wave*16+15 (m89-verified maps:
  //   A: lane row=lane&15, k=(lane>>4)*8+j; B: col=lane&15, same k;
  //   C: col=lane&15, row=(lane>>4)*4+r)
  s16x8 a0, a1;
  {
    const int arow = lane & 15;
    const int kgA = (lane >> 4) * 8;
    const int row = wave * 16 + arow;
    const int sw = (row >> 2) & 7;
    {
      int q0 = kgA >> 2;
      float4 f0 = xs4[row * 16 + (q0 ^ sw)];
      float4 f1 = xs4[row * 16 + ((q0 + 1) ^ sw)];
      a0[0] = f2bf(f0.x); a0[1] = f2bf(f0.y); a0[2] = f2bf(f0.z); a0[3] = f2bf(f0.w);
      a0[4] = f2bf(f1.x); a0[5] = f2bf(f1.y); a0[6] = f2bf(f1.z); a0[7] = f2bf(f1.w);
    }
    {
      int q0 = (32 + kgA) >> 2;
      float4 f0 = xs4[row * 16 + (q0 ^ sw)];
      float4 f1 = xs4[row * 16 + ((q0 + 1) ^ sw)];
      a1[0] = f2bf(f0.x); a1[1] = f2bf(f0.y); a1[2] = f2bf(f0.z); a1[3] = f2bf(f0.w);
      a1[4] = f2bf(f1.x); a1[5] = f2bf(f1.y); a1[6] = f2bf(f1.z); a1[7] = f2bf(f1.w);
    }
  }
  __syncthreads();   // x tile dead; smem becomes bbuf[2][16KB]

  const int ccol = lane & 15;
  const int kg   = (lane >> 4) * 8;
  const int swb  = (ccol & 7) << 3;                // lane-constant
  const int rowbase = wave * 16 + (lane >> 4) * 4;

  // stage tile t (16 KB) into buffer b: 512 threads x 2 x 16B
  auto STAGE = [&](int t, int b) {
    const char* s0 = (const char*)cbh + (size_t)t * 16384 + wave * 2048 + lane * 16;
    char* d0 = smem + b * 16384 + wave * 2048;
    gload_lds16(s0, d0);
    gload_lds16(s0 + 1024, d0 + 1024);
  };

  // ================= pass 1: per-row screen min =================
  float minv[4];
  minv[0] = minv[1] = minv[2] = minv[3] = FLT_MAX;

  STAGE(0, 0);
  __syncthreads();
  for (int t = 0; t < NT; ++t) {
    if (t + 1 < NT) STAGE(t + 1, (t + 1) & 1);
    const unsigned short* B = (const unsigned short*)(smem + (t & 1) * 16384);
#pragma unroll
    for (int st = 0; st < 8; ++st) {
      const unsigned short* bp = B + (st * 16 + ccol) * 64;
      s16x8 b0 = *(const s16x8*)(bp + (kg ^ swb));
      s16x8 b1 = *(const s16x8*)(bp + ((32 + kg) ^ swb));
      f32x4 acc = {0.f, 0.f, 0.f, 0.f};
      acc = __builtin_amdgcn_mfma_f32_16x16x32_bf16(a0, b0, acc, 0, 0, 0);
      acc = __builtin_amdgcn_mfma_f32_16x16x32_bf16(a1, b1, acc, 0, 0, 0);
#pragma unroll
      for (int r = 0; r < 4; ++r) minv[r] = fminf(minv[r], acc[r]);
    }
    __syncthreads();
  }

  // per-row min across the 16 covering lanes (rows are wave-private)
#pragma unroll
  for (int r = 0; r < 4; ++r) {
    float v = minv[r];
#pragma unroll
    for (int m = 1; m <= 8; m <<= 1) v = fminf(v, __shfl_xor(v, m));
    minv[r] = v;
  }
  if ((lane & 15) == 0) {
#pragma unroll
    for (int r = 0; r < 4; ++r)
      rowthr_s[rowbase + r] = minv[r] + MARGIN;
  }
  __syncthreads();

  float thr[4];
#pragma unroll
  for (int r = 0; r < 4; ++r)
    thr[r] = rowthr_s[rowbase + r];

  // ====== pass 2: recompute (bit-identical), collect candidates ======
  STAGE(0, 0);
  __syncthreads();
  for (int t = 0; t < NT; ++t) {
    if (t + 1 < NT) STAGE(t + 1, (t + 1) & 1);
    const unsigned short* B = (const unsigned short*)(smem + (t & 1) * 16384);
#pragma unroll
    for (int st = 0; st < 8; ++st) {
      const unsigned short* bp = B + (st * 16 + ccol) * 64;
      s16x8 b0 = *(const s16x8*)(bp + (kg ^ swb));
      s16x8 b1 = *(const s16x8*)(bp + ((32 + kg) ^ swb));
      f32x4 acc = {0.f, 0.f, 0.f, 0.f};
      acc = __builtin_amdgcn_mfma_f32_16x16x32_bf16(a0, b0, acc, 0, 0, 0);
      acc = __builtin_amdgcn_mfma_f32_16x16x32_bf16(a1, b1, acc, 0, 0, 0);
#pragma unroll
      for (int r = 0; r < 4; ++r) {
        if (acc[r] <= thr[r]) {
          int row = rowbase + r;
          int pos = atomicAdd(&cnt_s[row], 1);
          if (pos < CAND_CAP) cand_s[row * CAND_CAP + pos] = t * KT + st * 16 + ccol;
        }
      }
    }
    __syncthreads();
  }

  // ====== exact rescore (R-scheme), lex-(dist,k); 4 threads per row.
  //        x read from GLOBAL (linear d-order: verified-passing order). ======
  {
    const int row = tid >> 2, slot = tid & 3;
    const int cnt = cnt_s[row];
    if (cnt <= CAND_CAP) {
      const float* xr = x + (size_t)(row0 + row) * D_DIM;
      const float xq = xsq_s[row];
      float bv = FLT_MAX; int bk = INT_MAX;
      for (int i = slot; i < cnt; i += 4) {
        int k = cand_s[row * CAND_CAP + i];
        const float* er = cb + (size_t)k * D_DIM;
        float a = 0.f;
#pragma unroll 8
        for (int d = 0; d < D_DIM; ++d) a = fmaf(xr[d], er[d], a);
        float dist = (xq + esq[k]) - 2.0f * a;
        if (dist < bv || (dist == bv && k < bk)) { bv = dist; bk = k; }
      }
#pragma unroll
      for (int m = 1; m <= 2; m <<= 1) {
        float ov = __shfl_xor(bv, m); int ok = __shfl_xor(bk, m);
        if (ov < bv || (ov == bv && ok < bk)) { bv = ov; bk = ok; }
      }
      if (slot == 0) bestk_s[row] = bk;
    }
  }
  if (tid < BM && cnt_s[tid] > CAND_CAP) {
    int p = atomicAdd(&ovf_cnt, 1);
    ovf_rows[p] = tid;
  }
  __syncthreads();

  // ====== lossless overflow fallback: block-cooperative full scan ======
  {
    const int novf = ovf_cnt;
    for (int i = 0; i < novf; ++i) {
      const int row = ovf_rows[i];
      const float* xr = x + (size_t)(row0 + row) * D_DIM;
      const float xq = xsq_s[row];
      float bv = FLT_MAX; int bk = INT_MAX;
      for (int k = tid; k < K_CB; k += NTHREADS) {
        const float* er = cb + (size_t)k * D_DIM;
        float a = 0.f;
#pragma unroll 8
        for (int d = 0; d < D_DIM; ++d) a = fmaf(xr[d], er[d], a);
        float dist = (xq + esq[k]) - 2.0f * a;
        if (dist < bv || (dist == bv && k < bk)) { bv = dist; bk = k; }
      }
#pragma unroll
      for (int m = 1; m <= 32; m <<= 1) {
        float ov = __shfl_xor(bv, m); int ok = __shfl_xor(bk, m);
        if (ov < bv || (ov == bv && ok < bk)) { bv = ov; bk = ok; }
      }
      if (lane == 0) { fb_v[wave] = bv; fb_k[wave] = bk; }
      __syncthreads();
      if (tid == 0) {
        float BV = fb_v[0]; int BK = fb_k[0];
#pragma unroll
        for (int w = 1; w < NWAVES; ++w)
          if (fb_v[w] < BV || (fb_v[w] == BV && fb_k[w] < BK)) { BV = fb_v[w]; BK = fb_k[w]; }
        bestk_s[row] = BK;
      }
      __syncthreads();
    }
  }
  __syncthreads();

  // ---- gather: out[row] = codebook[bestk[row]], coalesced float4 ----
  const float4* cb4 = (const float4*)cb;
  float4* out4 = (float4*)out + (size_t)row0 * 16;
#pragma unroll
  for (int i = 0; i < 4; ++i) {
    int f = tid + i * NTHREADS;
    int row = f >> 4, c4 = f & 15;
    out4[f] = cb4[(size_t)bestk_s[row] * 16 + c4];
  }
}

extern "C" void kernel_launch(void* const* d_in, const int* in_sizes, int n_in,
                              void* d_out, int out_size, void* d_ws, size_t ws_size,
                              hipStream_t stream) {
  const float* x  = (const float*)d_in[0];   // [N, 64] fp32
  const float* cb = (const float*)d_in[1];   // [2048, 64] fp32
  float* out = (float*)d_out;                // [N, 64] fp32
  float* esq = (float*)d_ws;                 // [2048] fp32
  unsigned short* cbh = (unsigned short*)d_ws + 4096;  // swizzled bf16(-2e), 256 KB

  const int N = in_sizes[0] / D_DIM;         // 131072

  prep_kernel<<<(K_CB + 255) / 256, 256, 0, stream>>>(cb, esq, cbh);
  vq_mfma_kernel<<<N / BM, NTHREADS, 0, stream>>>(x, cb, esq, cbh, out);
}